// Round 14
// baseline (207.079 us; speedup 1.0000x reference)
//
#include <hip/hip_runtime.h>

#define M_TOT 32768   // B*T = 64*512
#define T_LEN 512
#define NIN   256
#define NH    1024
#define NOUT  256

typedef __attribute__((ext_vector_type(8))) short bf16x8;
typedef __attribute__((ext_vector_type(4))) float f32x4;
typedef unsigned short u16;
typedef unsigned int u32;

__device__ inline float bf2f(u16 u) {
  union { float f; unsigned int i; } v; v.i = ((unsigned int)u) << 16; return v.f;
}
__device__ inline u16 f2bf(float f) {
  union { float f; unsigned int i; } v; v.f = f;
  unsigned int r = v.i + 0x7FFFu + ((v.i >> 16) & 1u);
  return (u16)(r >> 16);
}

__device__ inline void gload_lds16(const void* g, void* l) {
  __builtin_amdgcn_global_load_lds(
      (const __attribute__((address_space(1))) void*)g,
      (__attribute__((address_space(3))) void*)l, 16, 0, 0);
}

#define PACK8(pk, v0, v1, SC)                                                     \
  pk.u[0] = f2bf((SC) * v0.x); pk.u[1] = f2bf((SC) * v0.y);                       \
  pk.u[2] = f2bf((SC) * v0.z); pk.u[3] = f2bf((SC) * v0.w);                       \
  pk.u[4] = f2bf((SC) * v1.x); pk.u[5] = f2bf((SC) * v1.y);                       \
  pk.u[6] = f2bf((SC) * v1.z); pk.u[7] = f2bf((SC) * v1.w);

// Wallf fragment-order map for logical element (row in [0,1024), c in [0,768)):
//   ct=row>>7, wcn=(row>>6)&1, nf=(row>>4)&3, lm=row&15
//   c<256: t=3*(c>>6); 256<=c<512: t=3*((c&255)>>6)+2; c>=512: t=3*((c&255)>>6)+1
//   kk=c&63, ks=kk>>5, kq=(kk>>3)&3, e=kk&7, lane=kq*16+lm
//   idx = (((ct*2+wcn)*12 + t)*8 + nf*2+ks)*512 + lane*8 + e

// ---------------- prep (vectorized x8): INz, WiT, Acat, Wallf Wi-panel, Wob ----------------
__global__ __launch_bounds__(256) void prep(const float* __restrict__ inp,
                                            const float* __restrict__ Wi,
                                            const float* __restrict__ Wih,
                                            const float* __restrict__ Whh,
                                            const float* __restrict__ Wo,
                                            u16* __restrict__ INz, u16* __restrict__ WiT,
                                            u16* __restrict__ Acat, u16* __restrict__ Wallf,
                                            u16* __restrict__ Wob) {
  const long gid = (long)blockIdx.x * blockDim.x + threadIdx.x;
  const long stride = (long)gridDim.x * blockDim.x;
  union { u16 u[8]; uint4 q; } pk;
  if (gid < 32) ((uint4*)INz)[gid] = make_uint4(0, 0, 0, 0);
  const long nv = (long)M_TOT * NIN / 8;
  for (long i = gid; i < nv; i += stride) {
    const float4* s = (const float4*)(inp + i * 8);
    float4 v0 = s[0], v1 = s[1];
    PACK8(pk, v0, v1, 1.0f);
    *(uint4*)(INz + 256 + i * 8) = pk.q;
  }
  for (long i = gid; i < 2048L * 1024 / 8; i += stride) {
    long j = i * 8, g = j >> 10, h = j & 1023;
    const float* s = (g < NH) ? (Wih + g * NH + h) : (Whh + (g - NH) * NH + h);
    float sc = (g < NH) ? 1.0f : 0.98f;
    float4 v0 = ((const float4*)s)[0], v1 = ((const float4*)s)[1];
    PACK8(pk, v0, v1, sc);
    *(uint4*)(Acat + j) = pk.q;
  }
  for (long i = gid; i < 256L * 1024; i += stride) {
    long it = i >> 10, h = i & 1023;
    WiT[i] = f2bf(Wi[h * NIN + it]);
  }
  // Wi panel -> Wallf (fragment order), vec8 (e=0..7 contiguous)
  for (long i = gid; i < 1024L * 256 / 8; i += stride) {
    long j = i * 8, g = j >> 8, k = j & 255;
    const float* sp = Wi + g * NIN + k;
    float4 v0 = ((const float4*)sp)[0], v1 = ((const float4*)sp)[1];
    PACK8(pk, v0, v1, 1.0f);
    int ctb = (int)(g >> 7), wc2 = (int)((g >> 6) & 1), nf2 = (int)((g >> 4) & 3);
    int lm2 = (int)(g & 15);
    int t2 = 3 * (int)(k >> 6) + 1;
    int kk = (int)(k & 63), ks2 = kk >> 5, kq2 = (kk >> 3) & 3;
    int lane2 = kq2 * 16 + lm2;
    size_t idx = ((size_t)(((ctb * 2 + wc2) * 12 + t2) * 8 + nf2 * 2 + ks2)) * 512 + lane2 * 8;
    *(uint4*)(Wallf + idx) = pk.q;
  }
  for (long i = gid; i < 256L * 1024 / 8; i += stride) {
    long j = i * 8;
    float4 v0 = ((const float4*)(Wo + j))[0], v1 = ((const float4*)(Wo + j))[1];
    PACK8(pk, v0, v1, 1.0f);
    *(uint4*)(Wob + j) = pk.q;
  }
}

// ---------------- wabbias: blocks 0..31 = wab GEMM (-> Wallf); 32..1055 = biasvec ----------------
__global__ __launch_bounds__(256) void wabbias(const u16* __restrict__ Acat,
                                               const u16* __restrict__ WiT,
                                               u16* __restrict__ Wallf,
                                               const float* __restrict__ Wih,
                                               const float* __restrict__ Whh,
                                               const float* __restrict__ bi,
                                               const float* __restrict__ bih,
                                               const float* __restrict__ bhh,
                                               float* __restrict__ bias1,
                                               float* __restrict__ bias2) {
  __shared__ __align__(16) u16 As[128 * 32];
  __shared__ __align__(16) u16 Bs[128 * 32];
  __shared__ float s1[256], s2[256];
  const int tid = threadIdx.x;
  if (blockIdx.x >= 32) {
    const int g = blockIdx.x - 32;
    float a1 = 0.f, a2 = 0.f;
#pragma unroll
    for (int q = 0; q < 4; q++) {
      int h = tid + q * 256;
      float bv = bi[h];
      a1 += Wih[(size_t)g * NH + h] * bv;
      a2 += Whh[(size_t)g * NH + h] * bv;
    }
    s1[tid] = a1; s2[tid] = a2;
    __syncthreads();
    for (int off = 128; off > 0; off >>= 1) {
      if (tid < off) { s1[tid] += s1[tid + off]; s2[tid] += s2[tid + off]; }
      __syncthreads();
    }
    if (tid == 0) {
      bias1[g] = s1[0] + bih[g] + bhh[g];
      bias2[g] = 0.98f * s2[0];
    }
    return;
  }
  const int r0 = (blockIdx.x & 15) * 128, c0 = (blockIdx.x >> 4) * 128;
  const int lane = tid & 63, wave = tid >> 6;
  const int wm = wave >> 1, wn = wave & 1;
  const int lm = lane & 15, kq = lane >> 4;

  f32x4 acc[4][4] = {};
  for (int k0 = 0; k0 < NH; k0 += 32) {
#pragma unroll
    for (int rr = 0; rr < 2; rr++) {
      int c = tid + rr * 256;
      int row = c >> 2, col = (c & 3) * 8;
      gload_lds16(Acat + (size_t)(r0 + row) * NH + k0 + col, (char*)As + c * 16);
      gload_lds16(WiT + (size_t)(c0 + row) * NH + k0 + col, (char*)Bs + c * 16);
    }
    __syncthreads();
    bf16x8 a[4], b[4];
#pragma unroll
    for (int i = 0; i < 4; i++) {
      a[i] = *(const bf16x8*)&As[(wm * 64 + i * 16 + lm) * 32 + kq * 8];
      b[i] = *(const bf16x8*)&Bs[(wn * 64 + i * 16 + lm) * 32 + kq * 8];
    }
#pragma unroll
    for (int i = 0; i < 4; i++)
#pragma unroll
      for (int jn = 0; jn < 4; jn++)
        acc[i][jn] = __builtin_amdgcn_mfma_f32_16x16x32_bf16(a[i], b[jn], acc[i][jn], 0, 0, 0);
    __syncthreads();
  }
#pragma unroll
  for (int i = 0; i < 4; i++) {
    int grb = r0 + wm * 64 + i * 16 + kq * 4;
#pragma unroll
    for (int jn = 0; jn < 4; jn++) {
      int gc = c0 + wn * 64 + jn * 16 + lm;
#pragma unroll
      for (int j = 0; j < 4; j++) {
        int g = grb + j;
        int row, c;
        if (g < NH) { row = g; c = gc; } else { row = g - NH; c = 256 + gc; }
        int ctb = row >> 7, wc2 = (row >> 6) & 1, nf2 = (row >> 4) & 3, lm2 = row & 15;
        int t2 = (c < 256) ? (3 * (c >> 6)) : (3 * ((c & 255) >> 6) + 2);
        int kk = c & 63, ks2 = kk >> 5, kq2 = (kk >> 3) & 3, e2 = kk & 7;
        int lane2 = kq2 * 16 + lm2;
        size_t idx = ((size_t)(((ctb * 2 + wc2) * 12 + t2) * 8 + nf2 * 2 + ks2)) * 512
                     + lane2 * 8 + e2;
        Wallf[idx] = f2bf(acc[i][jn][j]);
      }
    }
  }
}

// ---- fused12 v6: A in LDS (shared IN_t/IN_prev via row shift); B direct from
// ---- L2 in fragment order, double-buffered in registers. 7 barriers total.
// Tile order: {Wa_p, Wi_p, Wb_p} for p=0..3.
__global__ __launch_bounds__(256, 2) void fused12(const u16* __restrict__ INz,
                                                  const u16* __restrict__ Wallf,
                                                  const float* __restrict__ bi,
                                                  const float* __restrict__ bias1,
                                                  const float* __restrict__ bias2,
                                                  float* __restrict__ out0) {
  __shared__ __align__(16) u16 As[2][128 * 64];   // 2 x 16 KB
  __shared__ __align__(16) u16 row0s[256];        // IN_prev row for gr==r0 (or zeros)
  const int tid = threadIdx.x;
  const int bid = blockIdx.x;
  const int s = (bid & 7) * 256 + (bid >> 3);     // bijective XCD swizzle (2048 = 8*256)
  const int r0 = (s >> 3) * 128;
  const int c0s = s & 7;                          // c0 = c0s*128
  const int wave = tid >> 6, lane = tid & 63;
  const int wrm = wave >> 1, wcn = wave & 1;      // 2x2 wave grid, 64x64 out each
  const int lm = lane & 15, kq = lane >> 4;

  const int rr = tid >> 3;
  const int l = (tid & 7) ^ (rr & 7);
  const u16* aTb = INz + (size_t)(r0 + rr + 1) * NIN + l * 8;   // IN_t, group 0
  const u32 aD = (u32)tid * 16;
  const bool zrow = ((r0 & (T_LEN - 1)) == 0);
  const u16* r0src = INz + (size_t)(zrow ? 0 : r0) * NIN;       // zero row at seq boundary
  const u16* wfB = Wallf + (size_t)(c0s * 2 + wcn) * 96 * 512 + (size_t)lane * 8;

#define IS_A(bufi, i, P)                                                          \
  gload_lds16(aTb + (size_t)(i) * 32 * NIN + (P) * 64,                            \
              (char*)&As[bufi][0] + aD + (i) * 4096)
#define STAGE_A(bufi, P) { IS_A(bufi, 0, P); IS_A(bufi, 1, P); IS_A(bufi, 2, P); IS_A(bufi, 3, P); }
#define LOADB(ARR, T)                                                             \
  { _Pragma("unroll") for (int f = 0; f < 8; f++)                                 \
      ARR[f] = *(const bf16x8*)(wfB + ((T) * 8 + f) * 512); }
#define DO_MFMA(ACC, BARR)                                                        \
  { _Pragma("unroll") for (int mf = 0; mf < 4; mf++)                              \
      _Pragma("unroll") for (int nf = 0; nf < 4; nf++) {                          \
        ACC[mf][nf] = __builtin_amdgcn_mfma_f32_16x16x32_bf16(af[mf][0],          \
            BARR[nf * 2 + 0], ACC[mf][nf], 0, 0, 0);                              \
        ACC[mf][nf] = __builtin_amdgcn_mfma_f32_16x16x32_bf16(af[mf][1],          \
            BARR[nf * 2 + 1], ACC[mf][nf], 0, 0, 0);                              \
      } }
#define WAITL0                                                                    \
  {                                                                               \
    asm volatile("s_waitcnt lgkmcnt(0)" ::: "memory");                            \
    __builtin_amdgcn_sched_barrier(0);                                            \
  }

  f32x4 accC[4][4] = {};
  f32x4 accX[4][4] = {};
  bf16x8 af[4][2];
  bf16x8 b0r[8], b1r[8];

  // prologue: row0 (1 op) + A(0) (4 ops) + B(0) regs (8 ops)
  if (tid < 32) gload_lds16(r0src + tid * 8, (char*)row0s + tid * 16);
  STAGE_A(0, 0);
  LOADB(b0r, 0);

#pragma unroll
  for (int t = 0; t < 12; t++) {
    const int p = t / 3, m = t % 3;
    if (m == 0) {
      if (t > 0) __builtin_amdgcn_s_barrier();        // A[(p+1)&1] free to overwrite
      if (p < 3) STAGE_A((p + 1) & 1, p + 1);
    }
    if (t < 11) {
      if ((t & 1) == 0) { LOADB(b1r, t + 1); } else { LOADB(b0r, t + 1); }
    }
    if (m == 0) {
      // ensure this wave's A(p) stage (and older row0) landed, then sync all waves
      if (p < 3) { asm volatile("s_waitcnt vmcnt(12)" ::: "memory"); }
      else       { asm volatile("s_waitcnt vmcnt(8)" ::: "memory"); }
      __builtin_amdgcn_sched_barrier(0);
      __builtin_amdgcn_s_barrier();
      const char* Ab = (const char*)&As[p & 1][0];
#pragma unroll
      for (int mf = 0; mf < 4; mf++)
#pragma unroll
        for (int ks = 0; ks < 2; ks++) {
          int row = wrm * 64 + mf * 16 + lm;
          int phys = (ks * 4 + kq) ^ (lm & 7);
          af[mf][ks] = *(const bf16x8*)(Ab + row * 128 + phys * 16);
        }
    } else if (m == 2) {
      const char* Ab = (const char*)&As[p & 1][0];
#pragma unroll
      for (int mf = 0; mf < 4; mf++) {
        int r = wrm * 64 + mf * 16 + lm;
        int rb = (r == 0) ? 0 : (r - 1);
#pragma unroll
        for (int ks = 0; ks < 2; ks++) {
          int phys = (ks * 4 + kq) ^ (rb & 7);
          af[mf][ks] = *(const bf16x8*)(Ab + rb * 128 + phys * 16);
        }
      }
      if (wrm == 0) {
#pragma unroll
        for (int ks = 0; ks < 2; ks++) {
          bf16x8 rz = *(const bf16x8*)&row0s[p * 64 + ks * 32 + kq * 8];
          af[0][ks] = (lm == 0) ? rz : af[0][ks];
        }
      }
    }
    if (m != 1) WAITL0;
    __builtin_amdgcn_s_setprio(1);
    if (m == 1) {
      if ((t & 1) == 0) { DO_MFMA(accX, b0r) } else { DO_MFMA(accX, b1r) }
    } else {
      if ((t & 1) == 0) { DO_MFMA(accC, b0r) } else { DO_MFMA(accC, b1r) }
    }
    __builtin_amdgcn_s_setprio(0);
  }
#undef IS_A
#undef STAGE_A
#undef LOADB
#undef DO_MFMA

  // ---- epilogue ----
  const int c0 = c0s * 128;
#pragma unroll
  for (int mf = 0; mf < 4; mf++) {
    int grb = r0 + wrm * 64 + mf * 16 + kq * 4;
#pragma unroll
    for (int nf = 0; nf < 4; nf++) {
      int gc = c0 + wcn * 64 + nf * 16 + lm;
      float b1 = bias1[gc], b2v = bias2[gc], biv = bi[gc];
#pragma unroll
      for (int j = 0; j < 4; j++) {
        int gr = grb + j;
        float bb2 = b1 + (((gr & (T_LEN - 1)) != 0) ? b2v : 0.0f);
        float cv = fmaxf(accC[mf][nf][j] + bb2, 0.0f);
        float x = accX[mf][nf][j] + biv;
        out0[(size_t)gr * NH + gc] = 0.98f * x + 0.02f * cv;
      }
    }
  }
}

// ---------------- GEMM3: OUT = H * Wo^T + bo  (A reg-staged f32->bf16) ----------------
__global__ __launch_bounds__(256) void gemm3(const float* __restrict__ H,
                                             const u16* __restrict__ Wob,
                                             const float* __restrict__ bo,
                                             float* __restrict__ out1) {
  __shared__ __align__(16) u16 As[128 * 32];
  __shared__ __align__(16) u16 Bs[128 * 32];
  const int tid = threadIdx.x;
  const int r0 = blockIdx.x * 128, c0 = blockIdx.y * 128;
  const int lane = tid & 63, wave = tid >> 6;
  const int wm = wave >> 1, wn = wave & 1;
  const int lm = lane & 15, kq = lane >> 4;

  f32x4 acc[4][4] = {};
  for (int k0 = 0; k0 < NH; k0 += 32) {
#pragma unroll
    for (int rr = 0; rr < 2; rr++) {
      int c = tid + rr * 256;
      int row = c >> 2, col = (c & 3) * 8;
      const float* src = H + (size_t)(r0 + row) * NH + k0 + col;
      float4 v0 = *(const float4*)src;
      float4 v1 = *(const float4*)(src + 4);
      union { u16 u[8]; uint4 q; } pk;
      PACK8(pk, v0, v1, 1.0f);
      *(uint4*)((char*)As + c * 16) = pk.q;
      gload_lds16(Wob + (size_t)(c0 + row) * NH + k0 + col, (char*)Bs + c * 16);
    }
    __syncthreads();
    bf16x8 a[4], b[4];
#pragma unroll
    for (int i = 0; i < 4; i++) {
      a[i] = *(const bf16x8*)&As[(wm * 64 + i * 16 + lm) * 32 + kq * 8];
      b[i] = *(const bf16x8*)&Bs[(wn * 64 + i * 16 + lm) * 32 + kq * 8];
    }
#pragma unroll
    for (int i = 0; i < 4; i++)
#pragma unroll
      for (int jn = 0; jn < 4; jn++)
        acc[i][jn] = __builtin_amdgcn_mfma_f32_16x16x32_bf16(a[i], b[jn], acc[i][jn], 0, 0, 0);
    __syncthreads();
  }
#pragma unroll
  for (int i = 0; i < 4; i++) {
    int grb = r0 + wm * 64 + i * 16 + kq * 4;
#pragma unroll
    for (int jn = 0; jn < 4; jn++) {
      int gc = c0 + wn * 64 + jn * 16 + lm;
      float bv = bo[gc];
#pragma unroll
      for (int j = 0; j < 4; j++)
        out1[(size_t)(grb + j) * NOUT + gc] = acc[i][jn][j] + bv;
    }
  }
}

extern "C" void kernel_launch(void* const* d_in, const int* in_sizes, int n_in,
                              void* d_out, int out_size, void* d_ws, size_t ws_size,
                              hipStream_t stream) {
  const float* inp = (const float*)d_in[0];
  const float* Wi  = (const float*)d_in[1];
  const float* bi  = (const float*)d_in[2];
  const float* Wih = (const float*)d_in[3];
  const float* bih = (const float*)d_in[4];
  const float* Whh = (const float*)d_in[5];
  const float* bhh = (const float*)d_in[6];
  const float* Wo  = (const float*)d_in[7];
  const float* bo  = (const float*)d_in[8];

  float* out0 = (float*)d_out;                       // hidden [32768,1024] f32
  float* out1 = out0 + (size_t)M_TOT * NH;           // output [32768,256]  f32

  char* ws = (char*)d_ws;
  u16* Acat  = (u16*)ws;                             //  2048 x 1024 bf16 =  4,194,304 B
  u16* WiT   = (u16*)(ws + 4194304);                 //   256 x 1024 bf16 =    524,288 B
  u16* Wallf = (u16*)(ws + 4718592);                 //  786,432 bf16     =  1,572,864 B
  u16* Wob   = (u16*)(ws + 6291456);                 //   256 x 1024 bf16 =    524,288 B
  float* bias1 = (float*)(ws + 6815744);             //  1024 f32 = 4096 B
  float* bias2 = (float*)(ws + 6819840);             //  1024 f32 = 4096 B
  // total ws usage: 6,823,936 B
  // INz lives in the out1 region (33.5 MB >= 16.8 MB); dead before gemm3 writes out1.
  u16* INz = (u16*)out1;                             // [1+32768][256] bf16 = 16,777,728 B

  hipLaunchKernelGGL(prep, dim3(2048), dim3(256), 0, stream,
                     inp, Wi, Wih, Whh, Wo, INz, WiT, Acat, Wallf, Wob);
  hipLaunchKernelGGL(wabbias, dim3(1056), dim3(256), 0, stream,
                     Acat, WiT, Wallf, Wih, Whh, bi, bih, bhh, bias1, bias2);
  hipLaunchKernelGGL(fused12, dim3(2048), dim3(256), 0, stream,
                     INz, Wallf, bi, bias1, bias2, out0);
  hipLaunchKernelGGL(gemm3, dim3(256, 2), dim3(256), 0, stream, out0, Wob, bo, out1);
}

// Round 15
// 130.310 us; speedup vs baseline: 1.5891x; 1.5891x over previous
//
#include <hip/hip_runtime.h>

#define M_TOT 32768   // B*T = 64*512
#define T_LEN 512
#define NIN   256
#define NH    1024
#define NOUT  256

typedef __attribute__((ext_vector_type(8))) short bf16x8;
typedef __attribute__((ext_vector_type(4))) float f32x4;
typedef unsigned short u16;
typedef unsigned int u32;

__device__ inline float bf2f(u16 u) {
  union { float f; unsigned int i; } v; v.i = ((unsigned int)u) << 16; return v.f;
}
__device__ inline u16 f2bf(float f) {
  union { float f; unsigned int i; } v; v.f = f;
  unsigned int r = v.i + 0x7FFFu + ((v.i >> 16) & 1u);
  return (u16)(r >> 16);
}

__device__ inline void gload_lds16(const void* g, void* l) {
  __builtin_amdgcn_global_load_lds(
      (const __attribute__((address_space(1))) void*)g,
      (__attribute__((address_space(3))) void*)l, 16, 0, 0);
}

#define PACK8(pk, v0, v1, SC)                                                     \
  pk.u[0] = f2bf((SC) * v0.x); pk.u[1] = f2bf((SC) * v0.y);                       \
  pk.u[2] = f2bf((SC) * v0.z); pk.u[3] = f2bf((SC) * v0.w);                       \
  pk.u[4] = f2bf((SC) * v1.x); pk.u[5] = f2bf((SC) * v1.y);                       \
  pk.u[6] = f2bf((SC) * v1.z); pk.u[7] = f2bf((SC) * v1.w);

// ---------------- prep (vectorized x8): INz, WiT, Acat, Wall[:,512:768], Wob ----------------
__global__ __launch_bounds__(256) void prep(const float* __restrict__ inp,
                                            const float* __restrict__ Wi,
                                            const float* __restrict__ Wih,
                                            const float* __restrict__ Whh,
                                            const float* __restrict__ Wo,
                                            u16* __restrict__ INz, u16* __restrict__ WiT,
                                            u16* __restrict__ Acat, u16* __restrict__ Wall,
                                            u16* __restrict__ Wob) {
  const long gid = (long)blockIdx.x * blockDim.x + threadIdx.x;
  const long stride = (long)gridDim.x * blockDim.x;
  union { u16 u[8]; uint4 q; } pk;
  if (gid < 32) ((uint4*)INz)[gid] = make_uint4(0, 0, 0, 0);
  const long nv = (long)M_TOT * NIN / 8;
  for (long i = gid; i < nv; i += stride) {
    const float4* s = (const float4*)(inp + i * 8);
    float4 v0 = s[0], v1 = s[1];
    PACK8(pk, v0, v1, 1.0f);
    *(uint4*)(INz + 256 + i * 8) = pk.q;
  }
  for (long i = gid; i < 2048L * 1024 / 8; i += stride) {
    long j = i * 8, g = j >> 10, h = j & 1023;
    const float* s = (g < NH) ? (Wih + g * NH + h) : (Whh + (g - NH) * NH + h);
    float sc = (g < NH) ? 1.0f : 0.98f;
    float4 v0 = ((const float4*)s)[0], v1 = ((const float4*)s)[1];
    PACK8(pk, v0, v1, sc);
    *(uint4*)(Acat + j) = pk.q;
  }
  for (long i = gid; i < 256L * 1024; i += stride) {
    long it = i >> 10, h = i & 1023;
    WiT[i] = f2bf(Wi[h * NIN + it]);
  }
  for (long i = gid; i < 1024L * 256 / 8; i += stride) {
    long j = i * 8, g = j >> 8, k = j & 255;
    const float* s = Wi + g * NIN + k;
    float4 v0 = ((const float4*)s)[0], v1 = ((const float4*)s)[1];
    PACK8(pk, v0, v1, 1.0f);
    *(uint4*)(Wall + g * 768 + 512 + k) = pk.q;
  }
  for (long i = gid; i < 256L * 1024 / 8; i += stride) {
    long j = i * 8;
    float4 v0 = ((const float4*)(Wo + j))[0], v1 = ((const float4*)(Wo + j))[1];
    PACK8(pk, v0, v1, 1.0f);
    *(uint4*)(Wob + j) = pk.q;
  }
}

// ---------------- wabbias: blocks 0..31 = wab GEMM; blocks 32..1055 = biasvec ----------------
__global__ __launch_bounds__(256) void wabbias(const u16* __restrict__ Acat,
                                               const u16* __restrict__ WiT,
                                               u16* __restrict__ Wall,
                                               const float* __restrict__ Wih,
                                               const float* __restrict__ Whh,
                                               const float* __restrict__ bi,
                                               const float* __restrict__ bih,
                                               const float* __restrict__ bhh,
                                               float* __restrict__ bias1,
                                               float* __restrict__ bias2) {
  __shared__ __align__(16) u16 As[128 * 32];
  __shared__ __align__(16) u16 Bs[128 * 32];
  __shared__ float s1[256], s2[256];
  const int tid = threadIdx.x;
  if (blockIdx.x >= 32) {
    const int g = blockIdx.x - 32;
    float a1 = 0.f, a2 = 0.f;
#pragma unroll
    for (int q = 0; q < 4; q++) {
      int h = tid + q * 256;
      float bv = bi[h];
      a1 += Wih[(size_t)g * NH + h] * bv;
      a2 += Whh[(size_t)g * NH + h] * bv;
    }
    s1[tid] = a1; s2[tid] = a2;
    __syncthreads();
    for (int off = 128; off > 0; off >>= 1) {
      if (tid < off) { s1[tid] += s1[tid + off]; s2[tid] += s2[tid + off]; }
      __syncthreads();
    }
    if (tid == 0) {
      bias1[g] = s1[0] + bih[g] + bhh[g];
      bias2[g] = 0.98f * s2[0];
    }
    return;
  }
  const int r0 = (blockIdx.x & 15) * 128, c0 = (blockIdx.x >> 4) * 128;
  const int lane = tid & 63, wave = tid >> 6;
  const int wm = wave >> 1, wn = wave & 1;
  const int lm = lane & 15, kq = lane >> 4;

  f32x4 acc[4][4] = {};
  for (int k0 = 0; k0 < NH; k0 += 32) {
#pragma unroll
    for (int rr = 0; rr < 2; rr++) {
      int c = tid + rr * 256;
      int row = c >> 2, col = (c & 3) * 8;
      gload_lds16(Acat + (size_t)(r0 + row) * NH + k0 + col, (char*)As + c * 16);
      gload_lds16(WiT + (size_t)(c0 + row) * NH + k0 + col, (char*)Bs + c * 16);
    }
    __syncthreads();
    bf16x8 a[4], b[4];
#pragma unroll
    for (int i = 0; i < 4; i++) {
      a[i] = *(const bf16x8*)&As[(wm * 64 + i * 16 + lm) * 32 + kq * 8];
      b[i] = *(const bf16x8*)&Bs[(wn * 64 + i * 16 + lm) * 32 + kq * 8];
    }
#pragma unroll
    for (int i = 0; i < 4; i++)
#pragma unroll
      for (int jn = 0; jn < 4; jn++)
        acc[i][jn] = __builtin_amdgcn_mfma_f32_16x16x32_bf16(a[i], b[jn], acc[i][jn], 0, 0, 0);
    __syncthreads();
  }
#pragma unroll
  for (int i = 0; i < 4; i++) {
    int grb = r0 + wm * 64 + i * 16 + kq * 4;
#pragma unroll
    for (int jn = 0; jn < 4; jn++) {
      int gc = c0 + wn * 64 + jn * 16 + lm;
#pragma unroll
      for (int j = 0; j < 4; j++) {
        int g = grb + j;
        size_t dst = (g < NH) ? ((size_t)g * 768 + gc)
                              : ((size_t)(g - NH) * 768 + 256 + gc);
        Wall[dst] = f2bf(acc[i][jn][j]);
      }
    }
  }
}

// ---- fused12 v5 (round-13 proven) + Hb bf16 hidden copy for gemm3 ----
// Tile order: {Wa_p, Wi_p, Wb_p} for p=0..3 (12 tiles).
__global__ __launch_bounds__(256, 2) void fused12(const u16* __restrict__ INz,
                                                  const u16* __restrict__ Wall,
                                                  const float* __restrict__ bi,
                                                  const float* __restrict__ bias1,
                                                  const float* __restrict__ bias2,
                                                  float* __restrict__ out0,
                                                  u16* __restrict__ Hb) {
  __shared__ __align__(16) u16 As[2][128 * 64];   // 2 x 16 KB
  __shared__ __align__(16) u16 Bs[2][128 * 64];   // 2 x 16 KB  (total 64 KB, 2 blocks/CU)
  const int tid = threadIdx.x;
  const int bid = blockIdx.x;
  const int s = (bid & 7) * 256 + (bid >> 3);     // bijective XCD swizzle (2048 = 8*256)
  const int r0 = (s >> 3) * 128, c0 = (s & 7) * 128;
  const int wave = tid >> 6, lane = tid & 63;
  const int wrm = wave >> 1, wcn = wave & 1;      // 2x2 wave grid, 64x64 out each
  const int lm = lane & 15, kq = lane >> 4;

  const int rr = tid >> 3;                        // 0..31
  const int l = (tid & 7) ^ (rr & 7);             // logical k-chunk for this phys slot
  const u16* aTb = INz + (size_t)(r0 + rr + 1) * NIN + l * 8;   // IN_t, group 0
  const u16* bb = Wall + (size_t)(c0 + rr) * 768 + l * 8;
  const u32 aD = (u32)tid * 16;

#define IS_A(bufi, i, P)                                                          \
  gload_lds16(aTb + (size_t)(i) * 32 * NIN + (P) * 64,                            \
              (char*)&As[bufi][0] + aD + (i) * 4096)
#define BOFF(T) (((T) % 3 == 0) ? (((T) / 3) * 64)                                \
                : (((T) % 3 == 1) ? (512 + ((T) / 3) * 64) : (256 + ((T) / 3) * 64)))
#define IS_B(bufi, i, T)                                                          \
  gload_lds16(bb + (size_t)(i) * 32 * 768 + BOFF(T),                              \
              (char*)&Bs[bufi][0] + aD + (i) * 4096)
#define STAGE_A(bufi, P) { IS_A(bufi, 0, P); IS_A(bufi, 1, P); IS_A(bufi, 2, P); IS_A(bufi, 3, P); }
#define STAGE_B(bufi, T) { IS_B(bufi, 0, T); IS_B(bufi, 1, T); IS_B(bufi, 2, T); IS_B(bufi, 3, T); }
#define WAITV8 asm volatile("s_waitcnt vmcnt(8)" ::: "memory")
#define WAITV4 asm volatile("s_waitcnt vmcnt(4)" ::: "memory")
#define WAITV0 asm volatile("s_waitcnt vmcnt(0)" ::: "memory")
#define WAITL0                                                                    \
  {                                                                               \
    asm volatile("s_waitcnt lgkmcnt(0)" ::: "memory");                            \
    __builtin_amdgcn_sched_barrier(0);                                            \
  }

  f32x4 accC[4][4] = {};
  f32x4 accX[4][4] = {};
  bf16x8 af[4][2];                                // held across each p-group

  bf16x8 r0f[4][2];
  const bool zrow = ((r0 & (T_LEN - 1)) == 0);    // sequence boundary: row is zeros
#pragma unroll
  for (int p = 0; p < 4; p++)
#pragma unroll
    for (int ks = 0; ks < 2; ks++)
      r0f[p][ks] = *(const bf16x8*)(INz + (size_t)r0 * NIN + p * 64 + ks * 32 + kq * 8);
  STAGE_A(0, 0);
  STAGE_B(0, 0);

#pragma unroll
  for (int t = 0; t < 12; t++) {
    const int p = t / 3, m = t % 3;
    const int Ap = p & 1;
    if (t < 11) STAGE_B((t + 1) & 1, t + 1);
    if (m == 0 && t < 9) STAGE_A((p + 1) & 1, p + 1);
    if (t == 11) { WAITV0; }
    else if (m == 0 && t < 9) { WAITV8; }
    else { WAITV4; }
    __builtin_amdgcn_s_barrier();
    const char* Ab = (const char*)&As[Ap][0];
    const char* Bb = (const char*)&Bs[t & 1][0];
    if (m == 0) {
#pragma unroll
      for (int mf = 0; mf < 4; mf++)
#pragma unroll
        for (int ks = 0; ks < 2; ks++) {
          int row = wrm * 64 + mf * 16 + lm;
          int phys = (ks * 4 + kq) ^ (lm & 7);
          af[mf][ks] = *(const bf16x8*)(Ab + row * 128 + phys * 16);
        }
    } else if (m == 2) {
#pragma unroll
      for (int mf = 0; mf < 4; mf++) {
        int r = wrm * 64 + mf * 16 + lm;
        int rb = (r == 0) ? 0 : (r - 1);
#pragma unroll
        for (int ks = 0; ks < 2; ks++) {
          int phys = (ks * 4 + kq) ^ (rb & 7);
          af[mf][ks] = *(const bf16x8*)(Ab + rb * 128 + phys * 16);
        }
      }
      if (wrm == 0) {
        bf16x8 z = {};
#pragma unroll
        for (int ks = 0; ks < 2; ks++) {
          bf16x8 sub = zrow ? z : r0f[p][ks];
          af[0][ks] = (lm == 0) ? sub : af[0][ks];
        }
      }
    }
    bf16x8 bf[4][2];
#pragma unroll
    for (int nf = 0; nf < 4; nf++)
#pragma unroll
      for (int ks = 0; ks < 2; ks++) {
        int row = wcn * 64 + nf * 16 + lm;
        int phys = (ks * 4 + kq) ^ (lm & 7);
        bf[nf][ks] = *(const bf16x8*)(Bb + row * 128 + phys * 16);
      }
    WAITL0;
    __builtin_amdgcn_s_setprio(1);
    if (m == 1) {
#pragma unroll
      for (int mf = 0; mf < 4; mf++)
#pragma unroll
        for (int nf = 0; nf < 4; nf++) {
          accX[mf][nf] = __builtin_amdgcn_mfma_f32_16x16x32_bf16(af[mf][0], bf[nf][0], accX[mf][nf], 0, 0, 0);
          accX[mf][nf] = __builtin_amdgcn_mfma_f32_16x16x32_bf16(af[mf][1], bf[nf][1], accX[mf][nf], 0, 0, 0);
        }
    } else {
#pragma unroll
      for (int mf = 0; mf < 4; mf++)
#pragma unroll
        for (int nf = 0; nf < 4; nf++) {
          accC[mf][nf] = __builtin_amdgcn_mfma_f32_16x16x32_bf16(af[mf][0], bf[nf][0], accC[mf][nf], 0, 0, 0);
          accC[mf][nf] = __builtin_amdgcn_mfma_f32_16x16x32_bf16(af[mf][1], bf[nf][1], accC[mf][nf], 0, 0, 0);
        }
    }
    __builtin_amdgcn_s_setprio(0);
    __builtin_amdgcn_s_barrier();
  }
#undef IS_A
#undef IS_B
#undef BOFF
#undef STAGE_A
#undef STAGE_B

  // ---- epilogue: f32 out0 + bf16 Hb (for gemm3) ----
#pragma unroll
  for (int mf = 0; mf < 4; mf++) {
    int grb = r0 + wrm * 64 + mf * 16 + kq * 4;
#pragma unroll
    for (int nf = 0; nf < 4; nf++) {
      int gc = c0 + wcn * 64 + nf * 16 + lm;
      float b1 = bias1[gc], b2v = bias2[gc], biv = bi[gc];
#pragma unroll
      for (int j = 0; j < 4; j++) {
        int gr = grb + j;
        float bb2 = b1 + (((gr & (T_LEN - 1)) != 0) ? b2v : 0.0f);
        float cv = fmaxf(accC[mf][nf][j] + bb2, 0.0f);
        float x = accX[mf][nf][j] + biv;
        float hv = 0.98f * x + 0.02f * cv;
        out0[(size_t)gr * NH + gc] = hv;
        Hb[(size_t)gr * NH + gc] = f2bf(hv);
      }
    }
  }
}

// ---------------- GEMM3: OUT = Hb * Wo^T + bo  (bf16 A via gload_lds) ----------------
__global__ __launch_bounds__(256) void gemm3(const u16* __restrict__ Hb,
                                             const u16* __restrict__ Wob,
                                             const float* __restrict__ bo,
                                             float* __restrict__ out1) {
  __shared__ __align__(16) u16 As[128 * 32];
  __shared__ __align__(16) u16 Bs[128 * 32];
  const int tid = threadIdx.x;
  const int r0 = blockIdx.x * 128, c0 = blockIdx.y * 128;
  const int lane = tid & 63, wave = tid >> 6;
  const int wm = wave >> 1, wn = wave & 1;
  const int lm = lane & 15, kq = lane >> 4;

  f32x4 acc[4][4] = {};
  for (int k0 = 0; k0 < NH; k0 += 32) {
#pragma unroll
    for (int rr = 0; rr < 2; rr++) {
      int c = tid + rr * 256;
      int row = c >> 2, col = (c & 3) * 8;
      gload_lds16(Hb + (size_t)(r0 + row) * NH + k0 + col, (char*)As + c * 16);
      gload_lds16(Wob + (size_t)(c0 + row) * NH + k0 + col, (char*)Bs + c * 16);
    }
    __syncthreads();
    bf16x8 a[4], b[4];
#pragma unroll
    for (int i = 0; i < 4; i++) {
      a[i] = *(const bf16x8*)&As[(wm * 64 + i * 16 + lm) * 32 + kq * 8];
      b[i] = *(const bf16x8*)&Bs[(wn * 64 + i * 16 + lm) * 32 + kq * 8];
    }
#pragma unroll
    for (int i = 0; i < 4; i++)
#pragma unroll
      for (int jn = 0; jn < 4; jn++)
        acc[i][jn] = __builtin_amdgcn_mfma_f32_16x16x32_bf16(a[i], b[jn], acc[i][jn], 0, 0, 0);
    __syncthreads();
  }
#pragma unroll
  for (int i = 0; i < 4; i++) {
    int grb = r0 + wm * 64 + i * 16 + kq * 4;
#pragma unroll
    for (int jn = 0; jn < 4; jn++) {
      int gc = c0 + wn * 64 + jn * 16 + lm;
      float bv = bo[gc];
#pragma unroll
      for (int j = 0; j < 4; j++)
        out1[(size_t)(grb + j) * NOUT + gc] = acc[i][jn][j] + bv;
    }
  }
}

extern "C" void kernel_launch(void* const* d_in, const int* in_sizes, int n_in,
                              void* d_out, int out_size, void* d_ws, size_t ws_size,
                              hipStream_t stream) {
  const float* inp = (const float*)d_in[0];
  const float* Wi  = (const float*)d_in[1];
  const float* bi  = (const float*)d_in[2];
  const float* Wih = (const float*)d_in[3];
  const float* bih = (const float*)d_in[4];
  const float* Whh = (const float*)d_in[5];
  const float* bhh = (const float*)d_in[6];
  const float* Wo  = (const float*)d_in[7];
  const float* bo  = (const float*)d_in[8];

  float* out0 = (float*)d_out;                       // hidden [32768,1024] f32
  float* out1 = out0 + (size_t)M_TOT * NH;           // output [32768,256]  f32

  char* ws = (char*)d_ws;
  // Phase 1 (prep/wabbias): Acat + WiT live in ws[0 .. 4.7 MB).
  // Phase 2 (fused12/gemm3): Hb (67 MB) reuses ws[0 .. 67 MB) — Acat/WiT dead.
  u16* Acat = (u16*)ws;                              //  2048 x 1024 bf16 =  4,194,304 B
  u16* WiT  = (u16*)(ws + 4194304);                  //   256 x 1024 bf16 =    524,288 B
  u16* Hb   = (u16*)ws;                              // 32768 x 1024 bf16 = 67,108,864 B (alias)
  u16* Wall = (u16*)(ws + 67108864);                 //  1024 x  768 bf16 =  1,572,864 B
  u16* Wob  = (u16*)(ws + 68681728);                 //   256 x 1024 bf16 =    524,288 B
  float* bias1 = (float*)(ws + 69206016);            //  1024 f32 = 4096 B
  float* bias2 = (float*)(ws + 69210112);            //  1024 f32 = 4096 B
  // total ws usage: 69,214,208 B (== round-1's proven footprint)
  // INz lives in the out1 region (33.5 MB >= 16.8 MB); dead before gemm3 writes out1.
  u16* INz = (u16*)out1;                             // [1+32768][256] bf16 = 16,777,728 B

  hipLaunchKernelGGL(prep, dim3(2048), dim3(256), 0, stream,
                     inp, Wi, Wih, Whh, Wo, INz, WiT, Acat, Wall, Wob);
  hipLaunchKernelGGL(wabbias, dim3(1056), dim3(256), 0, stream,
                     Acat, WiT, Wall, Wih, Whh, bi, bih, bhh, bias1, bias2);
  hipLaunchKernelGGL(fused12, dim3(2048), dim3(256), 0, stream,
                     INz, Wall, bi, bias1, bias2, out0, Hb);
  hipLaunchKernelGGL(gemm3, dim3(256, 2), dim3(256), 0, stream, Hb, Wob, bo, out1);
}

// Round 16
// 118.466 us; speedup vs baseline: 1.7480x; 1.1000x over previous
//
#include <hip/hip_runtime.h>

#define M_TOT 32768   // B*T = 64*512
#define T_LEN 512
#define NIN   256
#define NH    1024
#define NOUT  256

typedef __attribute__((ext_vector_type(8))) short bf16x8;
typedef __attribute__((ext_vector_type(4))) float f32x4;
typedef unsigned short u16;
typedef unsigned int u32;

__device__ inline float bf2f(u16 u) {
  union { float f; unsigned int i; } v; v.i = ((unsigned int)u) << 16; return v.f;
}
__device__ inline u16 f2bf(float f) {
  union { float f; unsigned int i; } v; v.f = f;
  unsigned int r = v.i + 0x7FFFu + ((v.i >> 16) & 1u);
  return (u16)(r >> 16);
}

__device__ inline void gload_lds16(const void* g, void* l) {
  __builtin_amdgcn_global_load_lds(
      (const __attribute__((address_space(1))) void*)g,
      (__attribute__((address_space(3))) void*)l, 16, 0, 0);
}

#define PACK8(pk, v0, v1, SC)                                                     \
  pk.u[0] = f2bf((SC) * v0.x); pk.u[1] = f2bf((SC) * v0.y);                       \
  pk.u[2] = f2bf((SC) * v0.z); pk.u[3] = f2bf((SC) * v0.w);                       \
  pk.u[4] = f2bf((SC) * v1.x); pk.u[5] = f2bf((SC) * v1.y);                       \
  pk.u[6] = f2bf((SC) * v1.z); pk.u[7] = f2bf((SC) * v1.w);

// ---------------- prep (vectorized x8): INz, WiT, Acat, Wall[:,512:768], Wob ----------------
__global__ __launch_bounds__(256) void prep(const float* __restrict__ inp,
                                            const float* __restrict__ Wi,
                                            const float* __restrict__ Wih,
                                            const float* __restrict__ Whh,
                                            const float* __restrict__ Wo,
                                            u16* __restrict__ INz, u16* __restrict__ WiT,
                                            u16* __restrict__ Acat, u16* __restrict__ Wall,
                                            u16* __restrict__ Wob) {
  const long gid = (long)blockIdx.x * blockDim.x + threadIdx.x;
  const long stride = (long)gridDim.x * blockDim.x;
  union { u16 u[8]; uint4 q; } pk;
  if (gid < 32) ((uint4*)INz)[gid] = make_uint4(0, 0, 0, 0);
  const long nv = (long)M_TOT * NIN / 8;
  for (long i = gid; i < nv; i += stride) {
    const float4* s = (const float4*)(inp + i * 8);
    float4 v0 = s[0], v1 = s[1];
    PACK8(pk, v0, v1, 1.0f);
    *(uint4*)(INz + 256 + i * 8) = pk.q;
  }
  for (long i = gid; i < 2048L * 1024 / 8; i += stride) {
    long j = i * 8, g = j >> 10, h = j & 1023;
    const float* s = (g < NH) ? (Wih + g * NH + h) : (Whh + (g - NH) * NH + h);
    float sc = (g < NH) ? 1.0f : 0.98f;
    float4 v0 = ((const float4*)s)[0], v1 = ((const float4*)s)[1];
    PACK8(pk, v0, v1, sc);
    *(uint4*)(Acat + j) = pk.q;
  }
  for (long i = gid; i < 256L * 1024; i += stride) {
    long it = i >> 10, h = i & 1023;
    WiT[i] = f2bf(Wi[h * NIN + it]);
  }
  for (long i = gid; i < 1024L * 256 / 8; i += stride) {
    long j = i * 8, g = j >> 8, k = j & 255;
    const float* s = Wi + g * NIN + k;
    float4 v0 = ((const float4*)s)[0], v1 = ((const float4*)s)[1];
    PACK8(pk, v0, v1, 1.0f);
    *(uint4*)(Wall + g * 768 + 512 + k) = pk.q;
  }
  for (long i = gid; i < 256L * 1024 / 8; i += stride) {
    long j = i * 8;
    float4 v0 = ((const float4*)(Wo + j))[0], v1 = ((const float4*)(Wo + j))[1];
    PACK8(pk, v0, v1, 1.0f);
    *(uint4*)(Wob + j) = pk.q;
  }
}

// ---------------- wabbias: blocks 0..127 = wab GEMM (64x64 tiles); 128..1151 = biasvec ----------------
__global__ __launch_bounds__(256) void wabbias(const u16* __restrict__ Acat,
                                               const u16* __restrict__ WiT,
                                               u16* __restrict__ Wall,
                                               const float* __restrict__ Wih,
                                               const float* __restrict__ Whh,
                                               const float* __restrict__ bi,
                                               const float* __restrict__ bih,
                                               const float* __restrict__ bhh,
                                               float* __restrict__ bias1,
                                               float* __restrict__ bias2) {
  __shared__ __align__(16) u16 As[64 * 64];   // 8 KB
  __shared__ __align__(16) u16 Bs[64 * 64];   // 8 KB
  __shared__ float s1[256], s2[256];
  const int tid = threadIdx.x;
  if (blockIdx.x >= 128) {
    // ---- biasvec: b1[g]=bih+bhh+W_ih.bi ; b2[g]=0.98*W_hh.bi ----
    const int g = blockIdx.x - 128;
    float a1 = 0.f, a2 = 0.f;
#pragma unroll
    for (int q = 0; q < 4; q++) {
      int h = tid + q * 256;
      float bv = bi[h];
      a1 += Wih[(size_t)g * NH + h] * bv;
      a2 += Whh[(size_t)g * NH + h] * bv;
    }
    s1[tid] = a1; s2[tid] = a2;
    __syncthreads();
    for (int off = 128; off > 0; off >>= 1) {
      if (tid < off) { s1[tid] += s1[tid + off]; s2[tid] += s2[tid + off]; }
      __syncthreads();
    }
    if (tid == 0) {
      bias1[g] = s1[0] + bih[g] + bhh[g];
      bias2[g] = 0.98f * s2[0];
    }
    return;
  }
  // ---- wab: Wall[:,0:512] = [Wa | Wb], M=2048,N=256,K=1024; 64x64 tiles, 128 blocks ----
  // Per-output K-accumulation order identical to the 128^2 version -> bitwise-same Wall.
  const int r0 = (blockIdx.x & 31) * 64, c0 = (blockIdx.x >> 5) * 64;
  const int lane = tid & 63, wave = tid >> 6;
  const int wm = wave >> 1, wn = wave & 1;    // 2x2 waves, 32x32 out each
  const int lm = lane & 15, kq = lane >> 4;

  f32x4 acc[2][2] = {};
  for (int k0 = 0; k0 < NH; k0 += 64) {
#pragma unroll
    for (int h = 0; h < 2; h++) {
      int c = tid + h * 256;               // 512 chunks per panel, 2 per thread
      int r = c >> 3, p = c & 7;
      int l = p ^ (r & 7);                 // rule-21: inverse-swizzled source, linear dest
      gload_lds16(Acat + (size_t)(r0 + r) * NH + k0 + l * 8, (char*)As + c * 16);
      gload_lds16(WiT + (size_t)(c0 + r) * NH + k0 + l * 8, (char*)Bs + c * 16);
    }
    __syncthreads();
    bf16x8 a[2][2], b[2][2];
#pragma unroll
    for (int i = 0; i < 2; i++)
#pragma unroll
      for (int ks = 0; ks < 2; ks++) {
        int rowa = wm * 32 + i * 16 + lm;
        int rowb = wn * 32 + i * 16 + lm;
        int phys = (ks * 4 + kq) ^ (lm & 7);
        a[i][ks] = *(const bf16x8*)((const char*)As + rowa * 128 + phys * 16);
        b[i][ks] = *(const bf16x8*)((const char*)Bs + rowb * 128 + phys * 16);
      }
#pragma unroll
    for (int i = 0; i < 2; i++)
#pragma unroll
      for (int jn = 0; jn < 2; jn++) {
        acc[i][jn] = __builtin_amdgcn_mfma_f32_16x16x32_bf16(a[i][0], b[jn][0], acc[i][jn], 0, 0, 0);
        acc[i][jn] = __builtin_amdgcn_mfma_f32_16x16x32_bf16(a[i][1], b[jn][1], acc[i][jn], 0, 0, 0);
      }
    __syncthreads();
  }
#pragma unroll
  for (int i = 0; i < 2; i++) {
    int grb = r0 + wm * 32 + i * 16 + kq * 4;
#pragma unroll
    for (int jn = 0; jn < 2; jn++) {
      int gc = c0 + wn * 32 + jn * 16 + lm;
#pragma unroll
      for (int j = 0; j < 4; j++) {
        int g = grb + j;
        size_t dst = (g < NH) ? ((size_t)g * 768 + gc)
                              : ((size_t)(g - NH) * 768 + 256 + gc);
        Wall[dst] = f2bf(acc[i][jn][j]);
      }
    }
  }
}

// ---- fused12 v5 (round-13 proven): shared A tile for IN_t AND IN_prev (row-shift reuse) ----
// Tile order: {Wa_p, Wi_p, Wb_p} for p=0..3 (12 tiles).
__global__ __launch_bounds__(256, 2) void fused12(const u16* __restrict__ INz,
                                                  const u16* __restrict__ Wall,
                                                  const float* __restrict__ bi,
                                                  const float* __restrict__ bias1,
                                                  const float* __restrict__ bias2,
                                                  float* __restrict__ out0) {
  __shared__ __align__(16) u16 As[2][128 * 64];   // 2 x 16 KB
  __shared__ __align__(16) u16 Bs[2][128 * 64];   // 2 x 16 KB  (total 64 KB, 2 blocks/CU)
  const int tid = threadIdx.x;
  const int bid = blockIdx.x;
  const int s = (bid & 7) * 256 + (bid >> 3);     // bijective XCD swizzle (2048 = 8*256)
  const int r0 = (s >> 3) * 128, c0 = (s & 7) * 128;
  const int wave = tid >> 6, lane = tid & 63;
  const int wrm = wave >> 1, wcn = wave & 1;      // 2x2 wave grid, 64x64 out each
  const int lm = lane & 15, kq = lane >> 4;

  const int rr = tid >> 3;                        // 0..31
  const int l = (tid & 7) ^ (rr & 7);             // logical k-chunk for this phys slot
  const u16* aTb = INz + (size_t)(r0 + rr + 1) * NIN + l * 8;   // IN_t, group 0
  const u16* bb = Wall + (size_t)(c0 + rr) * 768 + l * 8;
  const u32 aD = (u32)tid * 16;

#define IS_A(bufi, i, P)                                                          \
  gload_lds16(aTb + (size_t)(i) * 32 * NIN + (P) * 64,                            \
              (char*)&As[bufi][0] + aD + (i) * 4096)
#define BOFF(T) (((T) % 3 == 0) ? (((T) / 3) * 64)                                \
                : (((T) % 3 == 1) ? (512 + ((T) / 3) * 64) : (256 + ((T) / 3) * 64)))
#define IS_B(bufi, i, T)                                                          \
  gload_lds16(bb + (size_t)(i) * 32 * 768 + BOFF(T),                              \
              (char*)&Bs[bufi][0] + aD + (i) * 4096)
#define STAGE_A(bufi, P) { IS_A(bufi, 0, P); IS_A(bufi, 1, P); IS_A(bufi, 2, P); IS_A(bufi, 3, P); }
#define STAGE_B(bufi, T) { IS_B(bufi, 0, T); IS_B(bufi, 1, T); IS_B(bufi, 2, T); IS_B(bufi, 3, T); }
#define WAITV8 asm volatile("s_waitcnt vmcnt(8)" ::: "memory")
#define WAITV4 asm volatile("s_waitcnt vmcnt(4)" ::: "memory")
#define WAITV0 asm volatile("s_waitcnt vmcnt(0)" ::: "memory")
#define WAITL0                                                                    \
  {                                                                               \
    asm volatile("s_waitcnt lgkmcnt(0)" ::: "memory");                            \
    __builtin_amdgcn_sched_barrier(0);                                            \
  }

  f32x4 accC[4][4] = {};
  f32x4 accX[4][4] = {};
  bf16x8 af[4][2];                                // held across each p-group

  bf16x8 r0f[4][2];
  const bool zrow = ((r0 & (T_LEN - 1)) == 0);    // sequence boundary: row is zeros
#pragma unroll
  for (int p = 0; p < 4; p++)
#pragma unroll
    for (int ks = 0; ks < 2; ks++)
      r0f[p][ks] = *(const bf16x8*)(INz + (size_t)r0 * NIN + p * 64 + ks * 32 + kq * 8);
  STAGE_A(0, 0);
  STAGE_B(0, 0);

#pragma unroll
  for (int t = 0; t < 12; t++) {
    const int p = t / 3, m = t % 3;
    const int Ap = p & 1;
    if (t < 11) STAGE_B((t + 1) & 1, t + 1);
    if (m == 0 && t < 9) STAGE_A((p + 1) & 1, p + 1);
    if (t == 11) { WAITV0; }
    else if (m == 0 && t < 9) { WAITV8; }
    else { WAITV4; }
    __builtin_amdgcn_s_barrier();
    const char* Ab = (const char*)&As[Ap][0];
    const char* Bb = (const char*)&Bs[t & 1][0];
    if (m == 0) {
#pragma unroll
      for (int mf = 0; mf < 4; mf++)
#pragma unroll
        for (int ks = 0; ks < 2; ks++) {
          int row = wrm * 64 + mf * 16 + lm;
          int phys = (ks * 4 + kq) ^ (lm & 7);
          af[mf][ks] = *(const bf16x8*)(Ab + row * 128 + phys * 16);
        }
    } else if (m == 2) {
#pragma unroll
      for (int mf = 0; mf < 4; mf++) {
        int r = wrm * 64 + mf * 16 + lm;
        int rb = (r == 0) ? 0 : (r - 1);
#pragma unroll
        for (int ks = 0; ks < 2; ks++) {
          int phys = (ks * 4 + kq) ^ (rb & 7);
          af[mf][ks] = *(const bf16x8*)(Ab + rb * 128 + phys * 16);
        }
      }
      if (wrm == 0) {
        bf16x8 z = {};
#pragma unroll
        for (int ks = 0; ks < 2; ks++) {
          bf16x8 sub = zrow ? z : r0f[p][ks];
          af[0][ks] = (lm == 0) ? sub : af[0][ks];
        }
      }
    }
    bf16x8 bf[4][2];
#pragma unroll
    for (int nf = 0; nf < 4; nf++)
#pragma unroll
      for (int ks = 0; ks < 2; ks++) {
        int row = wcn * 64 + nf * 16 + lm;
        int phys = (ks * 4 + kq) ^ (lm & 7);
        bf[nf][ks] = *(const bf16x8*)(Bb + row * 128 + phys * 16);
      }
    WAITL0;
    __builtin_amdgcn_s_setprio(1);
    if (m == 1) {
#pragma unroll
      for (int mf = 0; mf < 4; mf++)
#pragma unroll
        for (int nf = 0; nf < 4; nf++) {
          accX[mf][nf] = __builtin_amdgcn_mfma_f32_16x16x32_bf16(af[mf][0], bf[nf][0], accX[mf][nf], 0, 0, 0);
          accX[mf][nf] = __builtin_amdgcn_mfma_f32_16x16x32_bf16(af[mf][1], bf[nf][1], accX[mf][nf], 0, 0, 0);
        }
    } else {
#pragma unroll
      for (int mf = 0; mf < 4; mf++)
#pragma unroll
        for (int nf = 0; nf < 4; nf++) {
          accC[mf][nf] = __builtin_amdgcn_mfma_f32_16x16x32_bf16(af[mf][0], bf[nf][0], accC[mf][nf], 0, 0, 0);
          accC[mf][nf] = __builtin_amdgcn_mfma_f32_16x16x32_bf16(af[mf][1], bf[nf][1], accC[mf][nf], 0, 0, 0);
        }
    }
    __builtin_amdgcn_s_setprio(0);
    __builtin_amdgcn_s_barrier();
  }
#undef IS_A
#undef IS_B
#undef BOFF
#undef STAGE_A
#undef STAGE_B

  // ---- epilogue ----
#pragma unroll
  for (int mf = 0; mf < 4; mf++) {
    int grb = r0 + wrm * 64 + mf * 16 + kq * 4;
#pragma unroll
    for (int nf = 0; nf < 4; nf++) {
      int gc = c0 + wcn * 64 + nf * 16 + lm;
      float b1 = bias1[gc], b2v = bias2[gc], biv = bi[gc];
#pragma unroll
      for (int j = 0; j < 4; j++) {
        int gr = grb + j;
        float bb2 = b1 + (((gr & (T_LEN - 1)) != 0) ? b2v : 0.0f);
        float cv = fmaxf(accC[mf][nf][j] + bb2, 0.0f);
        float x = accX[mf][nf][j] + biv;
        out0[(size_t)gr * NH + gc] = 0.98f * x + 0.02f * cv;
      }
    }
  }
}

// ---------------- GEMM3: OUT = H * Wo^T + bo  (A reg-staged f32->bf16) ----------------
__global__ __launch_bounds__(256) void gemm3(const float* __restrict__ H,
                                             const u16* __restrict__ Wob,
                                             const float* __restrict__ bo,
                                             float* __restrict__ out1) {
  __shared__ __align__(16) u16 As[128 * 32];
  __shared__ __align__(16) u16 Bs[128 * 32];
  const int tid = threadIdx.x;
  const int r0 = blockIdx.x * 128, c0 = blockIdx.y * 128;
  const int lane = tid & 63, wave = tid >> 6;
  const int wm = wave >> 1, wn = wave & 1;
  const int lm = lane & 15, kq = lane >> 4;

  f32x4 acc[4][4] = {};
  for (int k0 = 0; k0 < NH; k0 += 32) {
#pragma unroll
    for (int rr = 0; rr < 2; rr++) {
      int c = tid + rr * 256;
      int row = c >> 2, col = (c & 3) * 8;
      const float* src = H + (size_t)(r0 + row) * NH + k0 + col;
      float4 v0 = *(const float4*)src;
      float4 v1 = *(const float4*)(src + 4);
      union { u16 u[8]; uint4 q; } pk;
      PACK8(pk, v0, v1, 1.0f);
      *(uint4*)((char*)As + c * 16) = pk.q;
      gload_lds16(Wob + (size_t)(c0 + row) * NH + k0 + col, (char*)Bs + c * 16);
    }
    __syncthreads();
    bf16x8 a[4], b[4];
#pragma unroll
    for (int i = 0; i < 4; i++) {
      a[i] = *(const bf16x8*)&As[(wm * 64 + i * 16 + lm) * 32 + kq * 8];
      b[i] = *(const bf16x8*)&Bs[(wn * 64 + i * 16 + lm) * 32 + kq * 8];
    }
#pragma unroll
    for (int i = 0; i < 4; i++)
#pragma unroll
      for (int jn = 0; jn < 4; jn++)
        acc[i][jn] = __builtin_amdgcn_mfma_f32_16x16x32_bf16(a[i], b[jn], acc[i][jn], 0, 0, 0);
    __syncthreads();
  }
#pragma unroll
  for (int i = 0; i < 4; i++) {
    int grb = r0 + wm * 64 + i * 16 + kq * 4;
#pragma unroll
    for (int jn = 0; jn < 4; jn++) {
      int gc = c0 + wn * 64 + jn * 16 + lm;
      float bv = bo[gc];
#pragma unroll
      for (int j = 0; j < 4; j++)
        out1[(size_t)(grb + j) * NOUT + gc] = acc[i][jn][j] + bv;
    }
  }
}

extern "C" void kernel_launch(void* const* d_in, const int* in_sizes, int n_in,
                              void* d_out, int out_size, void* d_ws, size_t ws_size,
                              hipStream_t stream) {
  const float* inp = (const float*)d_in[0];
  const float* Wi  = (const float*)d_in[1];
  const float* bi  = (const float*)d_in[2];
  const float* Wih = (const float*)d_in[3];
  const float* bih = (const float*)d_in[4];
  const float* Whh = (const float*)d_in[5];
  const float* bhh = (const float*)d_in[6];
  const float* Wo  = (const float*)d_in[7];
  const float* bo  = (const float*)d_in[8];

  float* out0 = (float*)d_out;                       // hidden [32768,1024] f32
  float* out1 = out0 + (size_t)M_TOT * NH;           // output [32768,256]  f32

  char* ws = (char*)d_ws;
  u16* Acat = (u16*)ws;                              //  2048 x 1024 bf16 =  4,194,304 B
  u16* WiT  = (u16*)(ws + 4194304);                  //   256 x 1024 bf16 =    524,288 B
  u16* Wall = (u16*)(ws + 4718592);                  //  1024 x  768 bf16 =  1,572,864 B
  u16* Wob  = (u16*)(ws + 6291456);                  //   256 x 1024 bf16 =    524,288 B
  float* bias1 = (float*)(ws + 6815744);             //  1024 f32 = 4096 B
  float* bias2 = (float*)(ws + 6819840);             //  1024 f32 = 4096 B
  // total ws usage: 6,823,936 B
  // INz lives in the out1 region (33.5 MB >= 16.8 MB); dead before gemm3 writes out1.
  u16* INz = (u16*)out1;                             // [1+32768][256] bf16 = 16,777,728 B

  hipLaunchKernelGGL(prep, dim3(2048), dim3(256), 0, stream,
                     inp, Wi, Wih, Whh, Wo, INz, WiT, Acat, Wall, Wob);
  hipLaunchKernelGGL(wabbias, dim3(1152), dim3(256), 0, stream,
                     Acat, WiT, Wall, Wih, Whh, bi, bih, bhh, bias1, bias2);
  hipLaunchKernelGGL(fused12, dim3(2048), dim3(256), 0, stream,
                     INz, Wall, bi, bias1, bias2, out0);
  hipLaunchKernelGGL(gemm3, dim3(256, 2), dim3(256), 0, stream, out0, Wob, bo, out1);
}